// Round 17
// baseline (209.759 us; speedup 1.0000x reference)
//
#include <hip/hip_runtime.h>

typedef unsigned short ushort_t;
typedef __bf16 bf16x8 __attribute__((ext_vector_type(8)));
typedef float floatx4 __attribute__((ext_vector_type(4)));

__device__ inline ushort_t f2bf(float f) {
    __bf16 h = (__bf16)f;
    return __builtin_bit_cast(ushort_t, h);
}

__device__ inline void gload16(const void* g, void* l) {
    __builtin_amdgcn_global_load_lds((const __attribute__((address_space(1))) void*)g,
                                     (__attribute__((address_space(3))) void*)l, 16, 0, 0);
}

// ---------------------------------------------------------------- prep: wt transpose (blocks 0..2303) + cast x (blocks 2304..8447)
__global__ __launch_bounds__(256) void prep_kernel(
    const float* __restrict__ x, ushort_t* __restrict__ xbf,
    const float* __restrict__ W0, const float* __restrict__ W1,
    const float* __restrict__ W2, const float* __restrict__ W3,
    ushort_t* __restrict__ T0, ushort_t* __restrict__ T1,
    ushort_t* __restrict__ T2, ushort_t* __restrict__ T3) {
    int bx = blockIdx.x;
    int tid = threadIdx.x;
    if (bx < 2304) {
        __shared__ float t[32][33];
        int w = bx / 576, rem = bx % 576;
        const float* W; ushort_t* T;
        switch (w) {
            case 0: W = W0; T = T0; break;
            case 1: W = W1; T = T1; break;
            case 2: W = W2; T = T2; break;
            default: W = W3; T = T3; break;
        }
        int n0 = (rem / 24) * 32, k0 = (rem % 24) * 32;
        int tx = tid & 31, ty = tid >> 5;   // 32 x 8
        for (int i = 0; i < 4; ++i)
            t[ty + i * 8][tx] = W[(k0 + ty + i * 8) * 768 + n0 + tx];
        __syncthreads();
        for (int i = 0; i < 4; ++i)
            T[(n0 + ty + i * 8) * 768 + k0 + tx] = f2bf(t[tx][ty + i * 8]);
    } else {
        int i = ((bx - 2304) * 256 + tid) * 4;
        float4 v = *(const float4*)(x + i);
        ushort4 u;
        u.x = f2bf(v.x); u.y = f2bf(v.y); u.z = f2bf(v.z); u.w = f2bf(v.w);
        *(ushort4*)(xbf + i) = u;
    }
}

// ---------------------------------------------------------------- fused QKV GEMM, A-reuse across Q/K/V (R16, measured win)
// grid (64, 12) = 768 blocks (3/CU). Each block stages its 128x64 A-tile ONCE
// per kt and multiplies against Bq/Bk/Bv for the same n0: 48 MFMA per 2
// barriers, 40KB staged per kt.
__global__ __launch_bounds__(256, 2) void gemm_qkv(
    const ushort_t* __restrict__ A,
    const ushort_t* __restrict__ Tq, const ushort_t* __restrict__ Tk, const ushort_t* __restrict__ Tv,
    const float* __restrict__ bq, const float* __restrict__ bk, const float* __restrict__ bv,
    ushort_t* __restrict__ Qb, ushort_t* __restrict__ Kb, ushort_t* __restrict__ Vtb) {
    __shared__ ushort_t sh[128 * 64 + 3 * 64 * 64];   // 40 KB: As | Bq | Bk | Bv; V-transpose reuses front
    int tid = threadIdx.x;
    int m0 = blockIdx.x * 128;
    int by = blockIdx.y;       // 0..11
    int n0 = by * 64;

    int wave = tid >> 6;
    int lane = tid & 63;
    int ln = tid & 15;
    int quad = (tid >> 4) & 3;
    int wm = wave * 32;          // wave's 32 M-rows
    int lr = lane >> 3;          // 0..7
    int lc = (lane & 7) * 8;     // element col in 64

    floatx4 acc[3][2][4];
    floatx4 z = {0.f, 0.f, 0.f, 0.f};
    for (int w = 0; w < 3; ++w)
        for (int i = 0; i < 2; ++i)
            for (int j = 0; j < 4; ++j) acc[w][i][j] = z;

    for (int kt = 0; kt < 12; ++kt) {
        int k0 = kt * 64;
        __syncthreads();
        for (int i = 0; i < 4; ++i) {            // A: 16 chunks of 8 rows
            int c = wave * 4 + i;
            gload16(&A[(m0 + c * 8 + lr) * 768 + k0 + lc], &sh[c * 512]);
        }
        for (int i = 0; i < 2; ++i) {            // B: 8 chunks per matrix
            int c = wave * 2 + i;
            int goff = (n0 + c * 8 + lr) * 768 + k0 + lc;
            gload16(&Tq[goff], &sh[8192 + c * 512]);
            gload16(&Tk[goff], &sh[12288 + c * 512]);
            gload16(&Tv[goff], &sh[16384 + c * 512]);
        }
        __syncthreads();
        for (int ks = 0; ks < 2; ++ks) {
            bf16x8 a[2];
            for (int i = 0; i < 2; ++i)
                a[i] = *(const bf16x8*)&sh[(wm + i * 16 + ln) * 64 + ks * 32 + quad * 8];
            for (int w = 0; w < 3; ++w) {
                const ushort_t* Bs = &sh[8192 + w * 4096];
                bf16x8 b[4];
                for (int j = 0; j < 4; ++j)
                    b[j] = *(const bf16x8*)&Bs[(j * 16 + ln) * 64 + ks * 32 + quad * 8];
                for (int i = 0; i < 2; ++i)
                    for (int j = 0; j < 4; ++j)
                        acc[w][i][j] = __builtin_amdgcn_mfma_f32_16x16x32_bf16(a[i], b[j], acc[w][i][j], 0, 0, 0);
            }
        }
    }

    const float QSCALE = 0.125f * 1.44269504088896f;  // fold softmax scale * log2(e)
    // Q and K: scatter epilogues
    for (int w = 0; w < 2; ++w) {
        const float* bias = w == 0 ? bq : bk;
        ushort_t* QK = w == 0 ? Qb : Kb;
        float scale = w == 0 ? QSCALE : 1.0f;
        for (int i = 0; i < 2; ++i) {
            for (int j = 0; j < 4; ++j) {
                int gn = n0 + j * 16 + ln;        // 0..767
                float bia = bias[gn];
                int h = gn >> 6, dd = gn & 63;
                for (int r = 0; r < 4; ++r) {
                    int gm = m0 + wm + i * 16 + quad * 4 + r;
                    int bb = gm >> 11, ss = gm & 2047;
                    QK[((bb * 12 + h) * 2048 + ss) * 64 + dd] = f2bf((acc[w][i][j][r] + bia) * scale);
                }
            }
        }
    }
    // V: transpose via LDS (pad 136), then coalesced dwordx4 stores
    __syncthreads();                               // staging LDS dead; reuse front of sh
    {
        ushort_t* tr = sh;                         // [64 n][136 m] = 8704 elems (17.4 KB)
        for (int j = 0; j < 4; ++j) {
            int nl = j * 16 + ln;                  // 0..63
            float bia = bv[n0 + nl];
            for (int i = 0; i < 2; ++i) {
                ushort4 u;
                u.x = f2bf(acc[2][i][j][0] + bia);
                u.y = f2bf(acc[2][i][j][1] + bia);
                u.z = f2bf(acc[2][i][j][2] + bia);
                u.w = f2bf(acc[2][i][j][3] + bia);
                *(ushort4*)&tr[nl * 136 + wm + i * 16 + quad * 4] = u;
            }
        }
        __syncthreads();
        int bb = m0 >> 11, ss0 = m0 & 2047;
        int head = by;                             // 0..11
        for (int p = 0; p < 4; ++p) {
            int n = p * 16 + (tid >> 4);           // 0..63
            int mc = (tid & 15) * 8;               // 0..120
            uint4 v = *(const uint4*)&tr[n * 136 + mc];
            *(uint4*)&Vtb[(size_t)((bb * 12 + head) * 64 + n) * 2048 + ss0 + mc] = v;
        }
    }
}

// ---------------------------------------------------------------- flash attention (R15-exact, measured ~65-67 us)
// XCD swizzle + (q-half x key-half) wave split. K and V register-staged into
// double-buffered LDS. launch_bounds(256,2) for the ~180-reg transient peak.
__global__ __launch_bounds__(256, 2) void attn_kernel(
    const ushort_t* __restrict__ Qb, const ushort_t* __restrict__ Kb,
    const ushort_t* __restrict__ Vtb, ushort_t* __restrict__ Ob) {
    __shared__ ushort_t shm[4 * 64 * 72];   // 36864 B: K0 | K1 | V0 | V1; merge overlay spans it
    const int PANEL = 64 * 72;              // 4608 ushorts per panel
    int tid = threadIdx.x;
    int bid = blockIdx.x;          // 0..767
    int swz = (bid & 7) * 96 + (bid >> 3);
    int bh = swz >> 4;             // 0..47
    int qt = swz & 15;             // 0..15
    int wave = tid >> 6;           // 0..3
    int qh = wave >> 1;            // q-half: 0 -> q 0..63, 1 -> q 64..127
    int kh = wave & 1;             // key-half: 0 -> keys 0..31, 1 -> keys 32..63
    int ln = tid & 15;
    int quad = (tid >> 4) & 3;
    int q0 = qt * 128 + qh * 64;   // this wave's 64 q-columns

    const ushort_t* Qp = Qb + (size_t)bh * 2048 * 64;
    const ushort_t* Kp = Kb + (size_t)bh * 2048 * 64;
    const ushort_t* Vp = Vtb + (size_t)bh * 64 * 2048;

    // Q B-fragments (loop-invariant): 4 q-groups of 16
    bf16x8 bqf[4][2];
    for (int g = 0; g < 4; ++g)
        for (int ks = 0; ks < 2; ++ks)
            bqf[g][ks] = *(const bf16x8*)&Qp[(q0 + g * 16 + ln) * 64 + ks * 32 + quad * 8];

    // staging indices (all 4 waves cooperate)
    int srow = tid >> 3;            // 0..31 (K rows / V d-rows)
    int c8 = tid & 7;               // 16B chunk within 64 keys
    int scol = c8 * 8;
    int u = c8 & 3;
    int vcol = (c8 >> 2) * 32 + (u & 1) * 16 + (u >> 1) * 4;   // sigma-permuted base

    uint4 kreg[2], vreg[2];

    // prologue: panel 0
    for (int p = 0; p < 2; ++p) {
        kreg[p] = *(const uint4*)&Kp[(p * 32 + srow) * 64 + scol];
        vreg[p] = *(const uint4*)&Vp[(p * 32 + srow) * 2048 + scol];
    }
    for (int p = 0; p < 2; ++p) {
        *(uint4*)&shm[(p * 32 + srow) * 72 + scol] = kreg[p];           // K0
        ushort_t* vb = &shm[2 * PANEL + (p * 32 + srow) * 72 + vcol];   // V0
        *(uint2*)vb = make_uint2(vreg[p].x, vreg[p].y);
        *(uint2*)(vb + 8) = make_uint2(vreg[p].z, vreg[p].w);
    }
    __syncthreads();

    floatx4 o_acc[4][4];           // [q-group][d-slice], this wave's key-half term
    float lsum[4] = {0.f, 0.f, 0.f, 0.f};
    floatx4 z = {0.f, 0.f, 0.f, 0.f};
    for (int g = 0; g < 4; ++g)
        for (int m4 = 0; m4 < 4; ++m4) o_acc[g][m4] = z;

    for (int kt = 0; kt < 32; ++kt) {
        int cur = kt & 1;
        if (kt < 31) {
            for (int p = 0; p < 2; ++p) {
                kreg[p] = *(const uint4*)&Kp[((kt + 1) * 64 + p * 32 + srow) * 64 + scol];
                vreg[p] = *(const uint4*)&Vp[(p * 32 + srow) * 2048 + (kt + 1) * 64 + scol];
            }
        }

        const ushort_t* KsH = shm + cur * PANEL;
        const ushort_t* VsH = shm + (2 + cur) * PANEL;

        // K A-frags: only our 2 key-slices (kh*32 .. kh*32+31)
        bf16x8 ak[2][2];
        for (int m = 0; m < 2; ++m)
            for (int ks = 0; ks < 2; ++ks)
                ak[m][ks] = *(const bf16x8*)&KsH[((kh * 2 + m) * 16 + ln) * 72 + ks * 32 + quad * 8];

        // S^T = K Q^T (32 keys x 64 q)
        floatx4 st[4][2];
        for (int g = 0; g < 4; ++g)
            for (int m = 0; m < 2; ++m) {
                floatx4 s = z;
                s = __builtin_amdgcn_mfma_f32_16x16x32_bf16(ak[m][0], bqf[g][0], s, 0, 0, 0);
                s = __builtin_amdgcn_mfma_f32_16x16x32_bf16(ak[m][1], bqf[g][1], s, 0, 0, 0);
                st[g][m] = s;
            }

        // P^T = 2^(S^T) in place; per-lane column partial sums
        for (int g = 0; g < 4; ++g)
            for (int m = 0; m < 2; ++m)
                for (int r = 0; r < 4; ++r) {
                    float e = __builtin_amdgcn_exp2f(st[g][m][r]);
                    st[g][m][r] = e;
                    lsum[g] += e;
                }

        // V^T A-frags: only our key-half (c = kh)
        bf16x8 av[4];
        for (int m4 = 0; m4 < 4; ++m4)
            av[m4] = *(const bf16x8*)&VsH[(m4 * 16 + ln) * 72 + kh * 32 + quad * 8];

        // Pack P^T B-frags (sigma order within our half) and accumulate O^T term
        for (int g = 0; g < 4; ++g) {
            bf16x8 b;
            b[0] = (__bf16)st[g][0][0];
            b[1] = (__bf16)st[g][0][1];
            b[2] = (__bf16)st[g][0][2];
            b[3] = (__bf16)st[g][0][3];
            b[4] = (__bf16)st[g][1][0];
            b[5] = (__bf16)st[g][1][1];
            b[6] = (__bf16)st[g][1][2];
            b[7] = (__bf16)st[g][1][3];
            for (int m4 = 0; m4 < 4; ++m4)
                o_acc[g][m4] = __builtin_amdgcn_mfma_f32_16x16x32_bf16(av[m4], b, o_acc[g][m4], 0, 0, 0);
        }

        // write prefetched panel into the other buffer
        if (kt < 31) {
            int nxt = cur ^ 1;
            ushort_t* Kn = shm + nxt * PANEL;
            ushort_t* Vn = shm + (2 + nxt) * PANEL;
            for (int p = 0; p < 2; ++p) {
                *(uint4*)&Kn[(p * 32 + srow) * 72 + scol] = kreg[p];
                ushort_t* vb = &Vn[(p * 32 + srow) * 72 + vcol];
                *(uint2*)vb = make_uint2(vreg[p].x, vreg[p].y);
                *(uint2*)(vb + 8) = make_uint2(vreg[p].z, vreg[p].w);
            }
        }
        __syncthreads();
    }

    // quad reduce: lsum[g] per lane -> sum over this wave's 32 keys (q = g*16+ln)
    for (int g = 0; g < 4; ++g) {
        lsum[g] += __shfl_xor(lsum[g], 16);
        lsum[g] += __shfl_xor(lsum[g], 32);
    }

    // merge the two key-half terms via LDS overlay on shm (35328 B <= 36864 B)
    float* mbuf = (float*)shm;                  // 2 x [64 q][68 f] = 34816 B
    float* lbuf = mbuf + 2 * 64 * 68;           // 128 floats
    if (kh == 1) {
        float* base = mbuf + qh * 64 * 68;
        for (int g = 0; g < 4; ++g) {
            for (int m4 = 0; m4 < 4; ++m4)
                *(floatx4*)&base[(g * 16 + ln) * 68 + m4 * 16 + quad * 4] = o_acc[g][m4];
            if (quad == 0) lbuf[qh * 64 + g * 16 + ln] = lsum[g];
        }
    }
    __syncthreads();

    int b = bh / 12, h = bh % 12;
    if (kh == 0) {
        float* base = mbuf + qh * 64 * 68;
        for (int g = 0; g < 4; ++g) {
            float inv = 1.f / (lsum[g] + lbuf[qh * 64 + g * 16 + ln]);
            int token = b * 2048 + q0 + g * 16 + ln;
            for (int m4 = 0; m4 < 4; ++m4) {
                floatx4 o2 = *(const floatx4*)&base[(g * 16 + ln) * 68 + m4 * 16 + quad * 4];
                for (int r = 0; r < 4; ++r)
                    Ob[token * 768 + h * 64 + m4 * 16 + quad * 4 + r] =
                        f2bf((o_acc[g][m4][r] + o2[r]) * inv);
            }
        }
    }
}

// ---------------------------------------------------------------- output projection (fp32 out), A-reuse across 3 n-slices
// grid (64,4) = 256 blocks (1/CU, uniform single round). Each block stages its
// 128x64 A-tile once per kt against 3 B-slices (n0 = by*192 + w*64): 48 MFMA
// per 2 barriers, 40KB LDS. Same verified inner loop as gemm_qkv.
__global__ __launch_bounds__(256, 2) void gemm_out(
    const ushort_t* __restrict__ A, const ushort_t* __restrict__ Bt,
    const float* __restrict__ bias, float* __restrict__ out) {
    __shared__ ushort_t sh[128 * 64 + 3 * 64 * 64];   // 40 KB: As | B0 | B1 | B2
    int tid = threadIdx.x;
    int m0 = blockIdx.x * 128;
    int nb = blockIdx.y * 192;     // 3 slices of 64

    int wave = tid >> 6;
    int lane = tid & 63;
    int ln = tid & 15;
    int quad = (tid >> 4) & 3;
    int wm = wave * 32;
    int lr = lane >> 3;
    int lc = (lane & 7) * 8;

    floatx4 acc[3][2][4];
    floatx4 z = {0.f, 0.f, 0.f, 0.f};
    for (int w = 0; w < 3; ++w)
        for (int i = 0; i < 2; ++i)
            for (int j = 0; j < 4; ++j) acc[w][i][j] = z;

    for (int kt = 0; kt < 12; ++kt) {
        int k0 = kt * 64;
        __syncthreads();
        for (int i = 0; i < 4; ++i) {            // A: 16 chunks of 8 rows
            int c = wave * 4 + i;
            gload16(&A[(m0 + c * 8 + lr) * 768 + k0 + lc], &sh[c * 512]);
        }
        for (int i = 0; i < 2; ++i) {            // B: 8 chunks per slice
            int c = wave * 2 + i;
            for (int w = 0; w < 3; ++w)
                gload16(&Bt[(nb + w * 64 + c * 8 + lr) * 768 + k0 + lc], &sh[8192 + w * 4096 + c * 512]);
        }
        __syncthreads();
        for (int ks = 0; ks < 2; ++ks) {
            bf16x8 a[2];
            for (int i = 0; i < 2; ++i)
                a[i] = *(const bf16x8*)&sh[(wm + i * 16 + ln) * 64 + ks * 32 + quad * 8];
            for (int w = 0; w < 3; ++w) {
                const ushort_t* Bs = &sh[8192 + w * 4096];
                bf16x8 b[4];
                for (int j = 0; j < 4; ++j)
                    b[j] = *(const bf16x8*)&Bs[(j * 16 + ln) * 64 + ks * 32 + quad * 8];
                for (int i = 0; i < 2; ++i)
                    for (int j = 0; j < 4; ++j)
                        acc[w][i][j] = __builtin_amdgcn_mfma_f32_16x16x32_bf16(a[i], b[j], acc[w][i][j], 0, 0, 0);
            }
        }
    }

    for (int w = 0; w < 3; ++w) {
        for (int i = 0; i < 2; ++i) {
            for (int j = 0; j < 4; ++j) {
                int gn = nb + w * 64 + j * 16 + ln;
                float bia = bias[gn];
                for (int r = 0; r < 4; ++r) {
                    int gm = m0 + wm + i * 16 + quad * 4 + r;
                    out[gm * 768 + gn] = acc[w][i][j][r] + bia;
                }
            }
        }
    }
}

extern "C" void kernel_launch(void* const* d_in, const int* in_sizes, int n_in,
                              void* d_out, int out_size, void* d_ws, size_t ws_size,
                              hipStream_t stream) {
    const float* x  = (const float*)d_in[0];
    const float* Wq = (const float*)d_in[1];
    const float* bq = (const float*)d_in[2];
    const float* Wk = (const float*)d_in[3];
    const float* bk = (const float*)d_in[4];
    const float* Wv = (const float*)d_in[5];
    const float* bv = (const float*)d_in[6];
    const float* Wo = (const float*)d_in[7];
    const float* bo = (const float*)d_in[8];

    const int NTOK = 4 * 2048;        // 8192
    const int NELT = NTOK * 768;      // 6291456
    const int WELT = 768 * 768;       // 589824

    ushort_t* xbf = (ushort_t*)d_ws;
    ushort_t* Tq  = xbf + NELT;
    ushort_t* Tk  = Tq + WELT;
    ushort_t* Tv  = Tk + WELT;
    ushort_t* To  = Tv + WELT;
    ushort_t* Qb  = To + WELT;
    ushort_t* Kb  = Qb + NELT;
    ushort_t* Vtb = Kb + NELT;
    ushort_t* Ob  = Vtb + NELT;

    prep_kernel<<<8448, 256, 0, stream>>>(x, xbf, Wq, Wk, Wv, Wo, Tq, Tk, Tv, To);
    gemm_qkv<<<dim3(64, 12), 256, 0, stream>>>(xbf, Tq, Tk, Tv, bq, bk, bv, Qb, Kb, Vtb);
    attn_kernel<<<768, 256, 0, stream>>>(Qb, Kb, Vtb, Ob);
    gemm_out<<<dim3(64, 4), 256, 0, stream>>>(Ob, To, bo, (float*)d_out);
}

// Round 18
// 205.341 us; speedup vs baseline: 1.0215x; 1.0215x over previous
//
#include <hip/hip_runtime.h>

typedef unsigned short ushort_t;
typedef __bf16 bf16x8 __attribute__((ext_vector_type(8)));
typedef float floatx4 __attribute__((ext_vector_type(4)));

__device__ inline ushort_t f2bf(float f) {
    __bf16 h = (__bf16)f;
    return __builtin_bit_cast(ushort_t, h);
}

__device__ inline void gload16(const void* g, void* l) {
    __builtin_amdgcn_global_load_lds((const __attribute__((address_space(1))) void*)g,
                                     (__attribute__((address_space(3))) void*)l, 16, 0, 0);
}

// ---------------------------------------------------------------- prep: wt transpose (blocks 0..2303) + cast x (blocks 2304..8447)
__global__ __launch_bounds__(256) void prep_kernel(
    const float* __restrict__ x, ushort_t* __restrict__ xbf,
    const float* __restrict__ W0, const float* __restrict__ W1,
    const float* __restrict__ W2, const float* __restrict__ W3,
    ushort_t* __restrict__ T0, ushort_t* __restrict__ T1,
    ushort_t* __restrict__ T2, ushort_t* __restrict__ T3) {
    int bx = blockIdx.x;
    int tid = threadIdx.x;
    if (bx < 2304) {
        __shared__ float t[32][33];
        int w = bx / 576, rem = bx % 576;
        const float* W; ushort_t* T;
        switch (w) {
            case 0: W = W0; T = T0; break;
            case 1: W = W1; T = T1; break;
            case 2: W = W2; T = T2; break;
            default: W = W3; T = T3; break;
        }
        int n0 = (rem / 24) * 32, k0 = (rem % 24) * 32;
        int tx = tid & 31, ty = tid >> 5;   // 32 x 8
        for (int i = 0; i < 4; ++i)
            t[ty + i * 8][tx] = W[(k0 + ty + i * 8) * 768 + n0 + tx];
        __syncthreads();
        for (int i = 0; i < 4; ++i)
            T[(n0 + ty + i * 8) * 768 + k0 + tx] = f2bf(t[tx][ty + i * 8]);
    } else {
        int i = ((bx - 2304) * 256 + tid) * 4;
        float4 v = *(const float4*)(x + i);
        ushort4 u;
        u.x = f2bf(v.x); u.y = f2bf(v.y); u.z = f2bf(v.z); u.w = f2bf(v.w);
        *(ushort4*)(xbf + i) = u;
    }
}

// ---------------------------------------------------------------- fused QKV GEMM, A-reuse across Q/K/V (R16, measured win)
// grid (64, 12) = 768 blocks (3/CU). Each block stages its 128x64 A-tile ONCE
// per kt and multiplies against Bq/Bk/Bv for the same n0: 48 MFMA per 2
// barriers, 40KB staged per kt.
__global__ __launch_bounds__(256, 2) void gemm_qkv(
    const ushort_t* __restrict__ A,
    const ushort_t* __restrict__ Tq, const ushort_t* __restrict__ Tk, const ushort_t* __restrict__ Tv,
    const float* __restrict__ bq, const float* __restrict__ bk, const float* __restrict__ bv,
    ushort_t* __restrict__ Qb, ushort_t* __restrict__ Kb, ushort_t* __restrict__ Vtb) {
    __shared__ ushort_t sh[128 * 64 + 3 * 64 * 64];   // 40 KB: As | Bq | Bk | Bv; V-transpose reuses front
    int tid = threadIdx.x;
    int m0 = blockIdx.x * 128;
    int by = blockIdx.y;       // 0..11
    int n0 = by * 64;

    int wave = tid >> 6;
    int lane = tid & 63;
    int ln = tid & 15;
    int quad = (tid >> 4) & 3;
    int wm = wave * 32;          // wave's 32 M-rows
    int lr = lane >> 3;          // 0..7
    int lc = (lane & 7) * 8;     // element col in 64

    floatx4 acc[3][2][4];
    floatx4 z = {0.f, 0.f, 0.f, 0.f};
    for (int w = 0; w < 3; ++w)
        for (int i = 0; i < 2; ++i)
            for (int j = 0; j < 4; ++j) acc[w][i][j] = z;

    for (int kt = 0; kt < 12; ++kt) {
        int k0 = kt * 64;
        __syncthreads();
        for (int i = 0; i < 4; ++i) {            // A: 16 chunks of 8 rows
            int c = wave * 4 + i;
            gload16(&A[(m0 + c * 8 + lr) * 768 + k0 + lc], &sh[c * 512]);
        }
        for (int i = 0; i < 2; ++i) {            // B: 8 chunks per matrix
            int c = wave * 2 + i;
            int goff = (n0 + c * 8 + lr) * 768 + k0 + lc;
            gload16(&Tq[goff], &sh[8192 + c * 512]);
            gload16(&Tk[goff], &sh[12288 + c * 512]);
            gload16(&Tv[goff], &sh[16384 + c * 512]);
        }
        __syncthreads();
        for (int ks = 0; ks < 2; ++ks) {
            bf16x8 a[2];
            for (int i = 0; i < 2; ++i)
                a[i] = *(const bf16x8*)&sh[(wm + i * 16 + ln) * 64 + ks * 32 + quad * 8];
            for (int w = 0; w < 3; ++w) {
                const ushort_t* Bs = &sh[8192 + w * 4096];
                bf16x8 b[4];
                for (int j = 0; j < 4; ++j)
                    b[j] = *(const bf16x8*)&Bs[(j * 16 + ln) * 64 + ks * 32 + quad * 8];
                for (int i = 0; i < 2; ++i)
                    for (int j = 0; j < 4; ++j)
                        acc[w][i][j] = __builtin_amdgcn_mfma_f32_16x16x32_bf16(a[i], b[j], acc[w][i][j], 0, 0, 0);
            }
        }
    }

    const float QSCALE = 0.125f * 1.44269504088896f;  // fold softmax scale * log2(e)
    // Q and K: scatter epilogues
    for (int w = 0; w < 2; ++w) {
        const float* bias = w == 0 ? bq : bk;
        ushort_t* QK = w == 0 ? Qb : Kb;
        float scale = w == 0 ? QSCALE : 1.0f;
        for (int i = 0; i < 2; ++i) {
            for (int j = 0; j < 4; ++j) {
                int gn = n0 + j * 16 + ln;        // 0..767
                float bia = bias[gn];
                int h = gn >> 6, dd = gn & 63;
                for (int r = 0; r < 4; ++r) {
                    int gm = m0 + wm + i * 16 + quad * 4 + r;
                    int bb = gm >> 11, ss = gm & 2047;
                    QK[((bb * 12 + h) * 2048 + ss) * 64 + dd] = f2bf((acc[w][i][j][r] + bia) * scale);
                }
            }
        }
    }
    // V: transpose via LDS (pad 136), then coalesced dwordx4 stores
    __syncthreads();                               // staging LDS dead; reuse front of sh
    {
        ushort_t* tr = sh;                         // [64 n][136 m] = 8704 elems (17.4 KB)
        for (int j = 0; j < 4; ++j) {
            int nl = j * 16 + ln;                  // 0..63
            float bia = bv[n0 + nl];
            for (int i = 0; i < 2; ++i) {
                ushort4 u;
                u.x = f2bf(acc[2][i][j][0] + bia);
                u.y = f2bf(acc[2][i][j][1] + bia);
                u.z = f2bf(acc[2][i][j][2] + bia);
                u.w = f2bf(acc[2][i][j][3] + bia);
                *(ushort4*)&tr[nl * 136 + wm + i * 16 + quad * 4] = u;
            }
        }
        __syncthreads();
        int bb = m0 >> 11, ss0 = m0 & 2047;
        int head = by;                             // 0..11
        for (int p = 0; p < 4; ++p) {
            int n = p * 16 + (tid >> 4);           // 0..63
            int mc = (tid & 15) * 8;               // 0..120
            uint4 v = *(const uint4*)&tr[n * 136 + mc];
            *(uint4*)&Vtb[(size_t)((bb * 12 + head) * 64 + n) * 2048 + ss0 + mc] = v;
        }
    }
}

// ---------------------------------------------------------------- flash attention (R15-exact, measured ~65-67 us)
// XCD swizzle + (q-half x key-half) wave split. K and V register-staged into
// double-buffered LDS. launch_bounds(256,2) for the ~180-reg transient peak.
__global__ __launch_bounds__(256, 2) void attn_kernel(
    const ushort_t* __restrict__ Qb, const ushort_t* __restrict__ Kb,
    const ushort_t* __restrict__ Vtb, ushort_t* __restrict__ Ob) {
    __shared__ ushort_t shm[4 * 64 * 72];   // 36864 B: K0 | K1 | V0 | V1; merge overlay spans it
    const int PANEL = 64 * 72;              // 4608 ushorts per panel
    int tid = threadIdx.x;
    int bid = blockIdx.x;          // 0..767
    int swz = (bid & 7) * 96 + (bid >> 3);
    int bh = swz >> 4;             // 0..47
    int qt = swz & 15;             // 0..15
    int wave = tid >> 6;           // 0..3
    int qh = wave >> 1;            // q-half: 0 -> q 0..63, 1 -> q 64..127
    int kh = wave & 1;             // key-half: 0 -> keys 0..31, 1 -> keys 32..63
    int ln = tid & 15;
    int quad = (tid >> 4) & 3;
    int q0 = qt * 128 + qh * 64;   // this wave's 64 q-columns

    const ushort_t* Qp = Qb + (size_t)bh * 2048 * 64;
    const ushort_t* Kp = Kb + (size_t)bh * 2048 * 64;
    const ushort_t* Vp = Vtb + (size_t)bh * 64 * 2048;

    // Q B-fragments (loop-invariant): 4 q-groups of 16
    bf16x8 bqf[4][2];
    for (int g = 0; g < 4; ++g)
        for (int ks = 0; ks < 2; ++ks)
            bqf[g][ks] = *(const bf16x8*)&Qp[(q0 + g * 16 + ln) * 64 + ks * 32 + quad * 8];

    // staging indices (all 4 waves cooperate)
    int srow = tid >> 3;            // 0..31 (K rows / V d-rows)
    int c8 = tid & 7;               // 16B chunk within 64 keys
    int scol = c8 * 8;
    int u = c8 & 3;
    int vcol = (c8 >> 2) * 32 + (u & 1) * 16 + (u >> 1) * 4;   // sigma-permuted base

    uint4 kreg[2], vreg[2];

    // prologue: panel 0
    for (int p = 0; p < 2; ++p) {
        kreg[p] = *(const uint4*)&Kp[(p * 32 + srow) * 64 + scol];
        vreg[p] = *(const uint4*)&Vp[(p * 32 + srow) * 2048 + scol];
    }
    for (int p = 0; p < 2; ++p) {
        *(uint4*)&shm[(p * 32 + srow) * 72 + scol] = kreg[p];           // K0
        ushort_t* vb = &shm[2 * PANEL + (p * 32 + srow) * 72 + vcol];   // V0
        *(uint2*)vb = make_uint2(vreg[p].x, vreg[p].y);
        *(uint2*)(vb + 8) = make_uint2(vreg[p].z, vreg[p].w);
    }
    __syncthreads();

    floatx4 o_acc[4][4];           // [q-group][d-slice], this wave's key-half term
    float lsum[4] = {0.f, 0.f, 0.f, 0.f};
    floatx4 z = {0.f, 0.f, 0.f, 0.f};
    for (int g = 0; g < 4; ++g)
        for (int m4 = 0; m4 < 4; ++m4) o_acc[g][m4] = z;

    for (int kt = 0; kt < 32; ++kt) {
        int cur = kt & 1;
        if (kt < 31) {
            for (int p = 0; p < 2; ++p) {
                kreg[p] = *(const uint4*)&Kp[((kt + 1) * 64 + p * 32 + srow) * 64 + scol];
                vreg[p] = *(const uint4*)&Vp[(p * 32 + srow) * 2048 + (kt + 1) * 64 + scol];
            }
        }

        const ushort_t* KsH = shm + cur * PANEL;
        const ushort_t* VsH = shm + (2 + cur) * PANEL;

        // K A-frags: only our 2 key-slices (kh*32 .. kh*32+31)
        bf16x8 ak[2][2];
        for (int m = 0; m < 2; ++m)
            for (int ks = 0; ks < 2; ++ks)
                ak[m][ks] = *(const bf16x8*)&KsH[((kh * 2 + m) * 16 + ln) * 72 + ks * 32 + quad * 8];

        // S^T = K Q^T (32 keys x 64 q)
        floatx4 st[4][2];
        for (int g = 0; g < 4; ++g)
            for (int m = 0; m < 2; ++m) {
                floatx4 s = z;
                s = __builtin_amdgcn_mfma_f32_16x16x32_bf16(ak[m][0], bqf[g][0], s, 0, 0, 0);
                s = __builtin_amdgcn_mfma_f32_16x16x32_bf16(ak[m][1], bqf[g][1], s, 0, 0, 0);
                st[g][m] = s;
            }

        // P^T = 2^(S^T) in place; per-lane column partial sums
        for (int g = 0; g < 4; ++g)
            for (int m = 0; m < 2; ++m)
                for (int r = 0; r < 4; ++r) {
                    float e = __builtin_amdgcn_exp2f(st[g][m][r]);
                    st[g][m][r] = e;
                    lsum[g] += e;
                }

        // V^T A-frags: only our key-half (c = kh)
        bf16x8 av[4];
        for (int m4 = 0; m4 < 4; ++m4)
            av[m4] = *(const bf16x8*)&VsH[(m4 * 16 + ln) * 72 + kh * 32 + quad * 8];

        // Pack P^T B-frags (sigma order within our half) and accumulate O^T term
        for (int g = 0; g < 4; ++g) {
            bf16x8 b;
            b[0] = (__bf16)st[g][0][0];
            b[1] = (__bf16)st[g][0][1];
            b[2] = (__bf16)st[g][0][2];
            b[3] = (__bf16)st[g][0][3];
            b[4] = (__bf16)st[g][1][0];
            b[5] = (__bf16)st[g][1][1];
            b[6] = (__bf16)st[g][1][2];
            b[7] = (__bf16)st[g][1][3];
            for (int m4 = 0; m4 < 4; ++m4)
                o_acc[g][m4] = __builtin_amdgcn_mfma_f32_16x16x32_bf16(av[m4], b, o_acc[g][m4], 0, 0, 0);
        }

        // write prefetched panel into the other buffer
        if (kt < 31) {
            int nxt = cur ^ 1;
            ushort_t* Kn = shm + nxt * PANEL;
            ushort_t* Vn = shm + (2 + nxt) * PANEL;
            for (int p = 0; p < 2; ++p) {
                *(uint4*)&Kn[(p * 32 + srow) * 72 + scol] = kreg[p];
                ushort_t* vb = &Vn[(p * 32 + srow) * 72 + vcol];
                *(uint2*)vb = make_uint2(vreg[p].x, vreg[p].y);
                *(uint2*)(vb + 8) = make_uint2(vreg[p].z, vreg[p].w);
            }
        }
        __syncthreads();
    }

    // quad reduce: lsum[g] per lane -> sum over this wave's 32 keys (q = g*16+ln)
    for (int g = 0; g < 4; ++g) {
        lsum[g] += __shfl_xor(lsum[g], 16);
        lsum[g] += __shfl_xor(lsum[g], 32);
    }

    // merge the two key-half terms via LDS overlay on shm (35328 B <= 36864 B)
    float* mbuf = (float*)shm;                  // 2 x [64 q][68 f] = 34816 B
    float* lbuf = mbuf + 2 * 64 * 68;           // 128 floats
    if (kh == 1) {
        float* base = mbuf + qh * 64 * 68;
        for (int g = 0; g < 4; ++g) {
            for (int m4 = 0; m4 < 4; ++m4)
                *(floatx4*)&base[(g * 16 + ln) * 68 + m4 * 16 + quad * 4] = o_acc[g][m4];
            if (quad == 0) lbuf[qh * 64 + g * 16 + ln] = lsum[g];
        }
    }
    __syncthreads();

    int b = bh / 12, h = bh % 12;
    if (kh == 0) {
        float* base = mbuf + qh * 64 * 68;
        for (int g = 0; g < 4; ++g) {
            float inv = 1.f / (lsum[g] + lbuf[qh * 64 + g * 16 + ln]);
            int token = b * 2048 + q0 + g * 16 + ln;
            for (int m4 = 0; m4 < 4; ++m4) {
                floatx4 o2 = *(const floatx4*)&base[(g * 16 + ln) * 68 + m4 * 16 + quad * 4];
                for (int r = 0; r < 4; ++r)
                    Ob[token * 768 + h * 64 + m4 * 16 + quad * 4 + r] =
                        f2bf((o_acc[g][m4][r] + o2[r]) * inv);
            }
        }
    }
}

// ---------------------------------------------------------------- output projection (fp32 out)
// 128Mx64N tiles -> grid (64,12) = 768 blocks (3/CU). R16-exact.
__global__ __launch_bounds__(256) void gemm_out(
    const ushort_t* __restrict__ A, const ushort_t* __restrict__ Bt,
    const float* __restrict__ bias, float* __restrict__ out) {
    __shared__ ushort_t As[128 * 64];   // 16 KB
    __shared__ ushort_t Bs[64 * 64];    // 8 KB
    int tid = threadIdx.x;
    int m0 = blockIdx.x * 128;
    int n0 = blockIdx.y * 64;

    int wave = tid >> 6;
    int lane = tid & 63;
    int ln = tid & 15;
    int quad = (tid >> 4) & 3;
    int wm = wave * 32;
    int lr = lane >> 3;
    int lc = (lane & 7) * 8;

    floatx4 acc[2][4];
    floatx4 z = {0.f, 0.f, 0.f, 0.f};
    for (int i = 0; i < 2; ++i)
        for (int j = 0; j < 4; ++j) acc[i][j] = z;

    for (int kt = 0; kt < 12; ++kt) {
        int k0 = kt * 64;
        __syncthreads();
        for (int i = 0; i < 4; ++i) {            // A: 16 chunks of 8 rows
            int c = wave * 4 + i;
            gload16(&A[(m0 + c * 8 + lr) * 768 + k0 + lc], &As[c * 512]);
        }
        for (int i = 0; i < 2; ++i) {            // B: 8 chunks
            int c = wave * 2 + i;
            gload16(&Bt[(n0 + c * 8 + lr) * 768 + k0 + lc], &Bs[c * 512]);
        }
        __syncthreads();
        for (int ks = 0; ks < 2; ++ks) {
            bf16x8 a[2], b[4];
            for (int i = 0; i < 2; ++i)
                a[i] = *(const bf16x8*)&As[(wm + i * 16 + ln) * 64 + ks * 32 + quad * 8];
            for (int j = 0; j < 4; ++j)
                b[j] = *(const bf16x8*)&Bs[(j * 16 + ln) * 64 + ks * 32 + quad * 8];
            for (int i = 0; i < 2; ++i)
                for (int j = 0; j < 4; ++j)
                    acc[i][j] = __builtin_amdgcn_mfma_f32_16x16x32_bf16(a[i], b[j], acc[i][j], 0, 0, 0);
        }
    }

    for (int i = 0; i < 2; ++i) {
        for (int j = 0; j < 4; ++j) {
            int gn = n0 + j * 16 + ln;
            float bia = bias[gn];
            for (int r = 0; r < 4; ++r) {
                int gm = m0 + wm + i * 16 + quad * 4 + r;
                out[gm * 768 + gn] = acc[i][j][r] + bia;
            }
        }
    }
}

extern "C" void kernel_launch(void* const* d_in, const int* in_sizes, int n_in,
                              void* d_out, int out_size, void* d_ws, size_t ws_size,
                              hipStream_t stream) {
    const float* x  = (const float*)d_in[0];
    const float* Wq = (const float*)d_in[1];
    const float* bq = (const float*)d_in[2];
    const float* Wk = (const float*)d_in[3];
    const float* bk = (const float*)d_in[4];
    const float* Wv = (const float*)d_in[5];
    const float* bv = (const float*)d_in[6];
    const float* Wo = (const float*)d_in[7];
    const float* bo = (const float*)d_in[8];

    const int NTOK = 4 * 2048;        // 8192
    const int NELT = NTOK * 768;      // 6291456
    const int WELT = 768 * 768;       // 589824

    ushort_t* xbf = (ushort_t*)d_ws;
    ushort_t* Tq  = xbf + NELT;
    ushort_t* Tk  = Tq + WELT;
    ushort_t* Tv  = Tk + WELT;
    ushort_t* To  = Tv + WELT;
    ushort_t* Qb  = To + WELT;
    ushort_t* Kb  = Qb + NELT;
    ushort_t* Vtb = Kb + NELT;
    ushort_t* Ob  = Vtb + NELT;

    prep_kernel<<<8448, 256, 0, stream>>>(x, xbf, Wq, Wk, Wv, Wo, Tq, Tk, Tv, To);
    gemm_qkv<<<dim3(64, 12), 256, 0, stream>>>(xbf, Tq, Tk, Tv, bq, bk, bv, Qb, Kb, Vtb);
    attn_kernel<<<768, 256, 0, stream>>>(Qb, Kb, Vtb, Ob);
    gemm_out<<<dim3(64, 12), 256, 0, stream>>>(Ob, To, bo, (float*)d_out);
}